// Round 7
// baseline (211.675 us; speedup 1.0000x reference)
//
#include <hip/hip_runtime.h>

// YOLO loss, round 13 = round 12 resubmitted (r12 bench died in infra:
// "MI355X container failed twice", no pytest/profile ran; static audit
// found no OOB / deadlock / LDS hazard — bounds verified exactly for
// cells=802816; COMPUTE has zero vmem ops so vmcnt counting is exact and
// vmcnt(N) can only weaken, never deadlock).
//
// Persistent depth-2 pipelined DMA streaming.
// r11 evidence: dense (176.6MB) == gated (~147MB) == ~54us -> access
// pattern is NOT the limiter. Reads run ~3.2 TB/s while fillBuffer WRITES
// 6.8 TB/s on the same runs: writes are fire-and-forget, reads need
// sustained outstanding demand (Little: ~9KB/CU at ~900cy, 10.2 B/cyc/CU).
// All prior rounds share the same hole: issue -> vmcnt(0) drain ->
// compute -> reduce -> exit -> relaunch. r12/r13 tests CONTINUOUS read
// pressure: 1 wave/block, 4 consecutive 64-cell tiles, double-buffered
// LDS, ALL streams via global_load_lds (15 DMA/tile), counted vmcnt(15)
// so the pipe never drains until the tail.
// Predict: FETCH ~176MB, WRITE ~0.1MB, occupancy ~15% (by design),
// yolo_main 29-38us, total 168-178. If ~193: read-path cap is real ->
// revert to r10, ROOFLINE.

#define SS 28
#define BLOCK 64

// LDS float offsets within one buffer (3520 floats = 14080 B)
#define P_OFF  0       // pred  1920 floats
#define TB_OFF 1920    // tbox   256 floats
#define TC_OFF 2176    // tcls  1280 floats
#define MK_OFF 3456    // mask    64 ints
#define BUFSZ  3520

typedef const __attribute__((address_space(1))) void* as1cp;
typedef __attribute__((address_space(3))) void* as3p;

__global__ __launch_bounds__(BLOCK) void yolo_main(
    const float4* __restrict__ pred4,   // [cells*30/4]
    const float4* __restrict__ tbox4,   // [cells]
    const float4* __restrict__ tcls4,   // [cells*5]
    const int*   __restrict__ mask,     // [cells]
    float4* __restrict__ block_part,    // [gridDim.x]
    int cells)                          // divisible by 256 (802816)
{
    __shared__ float lds[2 * BUFSZ];

    const int lane = threadIdx.x & 63;
    const int t0   = blockIdx.x * 4;    // first of 4 consecutive tiles

    float acc_cls = 0.f, acc_noobj = 0.f, acc_reg = 0.f, acc_cont = 0.f;

// ---- issue one tile's 15 DMA loads into buffer BUF ----
#define ISSUE(T, BUF)                                                        \
    {                                                                        \
        float* bp = lds + (BUF) * BUFSZ;                                     \
        const size_t pb4 = (size_t)(T) * 480;                                \
        _Pragma("unroll")                                                    \
        for (int it = 0; it < 8; ++it) {                                     \
            int p = it * 64 + lane;                                          \
            if (p < 480)  /* it=7: lanes 32-63 masked off (8 instrs) */      \
                __builtin_amdgcn_global_load_lds(                            \
                    (as1cp)(pred4 + pb4 + p),                                \
                    (as3p)(bp + P_OFF + it * 256), 16, 0, 0);                \
        }                                                                    \
        __builtin_amdgcn_global_load_lds(                                    \
            (as1cp)(tbox4 + (size_t)(T) * 64 + lane),                        \
            (as3p)(bp + TB_OFF), 16, 0, 0);                                  \
        _Pragma("unroll")                                                    \
        for (int it = 0; it < 5; ++it)                                       \
            __builtin_amdgcn_global_load_lds(                                \
                (as1cp)(tcls4 + (size_t)(T) * 320 + it * 64 + lane),         \
                (as3p)(bp + TC_OFF + it * 256), 16, 0, 0);                   \
        __builtin_amdgcn_global_load_lds(                                    \
            (as1cp)(mask + (size_t)(T) * 64 + lane),                         \
            (as3p)(bp + MK_OFF), 4, 0, 0);                                   \
    }

// wait until at most N vmem ops outstanding (in-order retire: the 15 of
// the oldest tile are drained when <=15 remain)
#define WAITV(N)                                                             \
    asm volatile("s_waitcnt vmcnt(" #N ")" ::: "memory");                    \
    __builtin_amdgcn_sched_barrier(0);

// all LDS reads of a buffer complete before its DMA overwrite is issued
#define LGKM0 asm volatile("s_waitcnt lgkmcnt(0)" ::: "memory");

// ---- full per-tile compute out of buffer BUF ----
#define COMPUTE(BUF)                                                         \
    {                                                                        \
        const float* bp = lds + (BUF) * BUFSZ;                               \
        const int*  mi = (const int*)(bp + MK_OFF);                          \
        int m = mi[lane];                                                    \
        const float* pr = bp + P_OFF + lane * 30;                            \
        if (!m) {                                                            \
            float c1 = pr[4], c2 = pr[9];                                    \
            acc_noobj += c1 * c1 + c2 * c2;                                  \
        } else {                                                             \
            const float4 tb = ((const float4*)(bp + TB_OFF))[lane];          \
            const float invS = 1.f / 28.f;                                   \
            float txc = tb.x * invS, tyc = tb.y * invS;                      \
            float t0_ = txc - 0.5f * tb.z, t1_ = tyc - 0.5f * tb.w;          \
            float t2_ = txc + 0.5f * tb.z, t3_ = tyc + 0.5f * tb.w;          \
            float ta = (t2_ - t0_) * (t3_ - t1_);                            \
            float b1xc = pr[0] * invS, b1yc = pr[1] * invS;                  \
            float a0 = b1xc - 0.5f * pr[2], a1 = b1yc - 0.5f * pr[3];        \
            float a2 = b1xc + 0.5f * pr[2], a3 = b1yc + 0.5f * pr[3];        \
            float wx = fmaxf(fminf(a2, t2_) - fmaxf(a0, t0_), 0.f);          \
            float wy = fmaxf(fminf(a3, t3_) - fmaxf(a1, t1_), 0.f);          \
            float inter = wx * wy;                                           \
            float area1 = (a2 - a0) * (a3 - a1);                             \
            float den = area1 + ta - inter;                                  \
            float iou1 = inter / (den > 0.f ? den : 1.f);                    \
            float b2xc = pr[5] * invS, b2yc = pr[6] * invS;                  \
            float e0 = b2xc - 0.5f * pr[7], e1 = b2yc - 0.5f * pr[8];        \
            float e2 = b2xc + 0.5f * pr[7], e3 = b2yc + 0.5f * pr[8];        \
            wx = fmaxf(fminf(e2, t2_) - fmaxf(e0, t0_), 0.f);                \
            wy = fmaxf(fminf(e3, t3_) - fmaxf(e1, t1_), 0.f);                \
            inter = wx * wy;                                                 \
            float area2 = (e2 - e0) * (e3 - e1);                             \
            den = area2 + ta - inter;                                        \
            float iou2 = inter / (den > 0.f ? den : 1.f);                    \
            bool take1 = iou1 > iou2;                                        \
            float best_iou = take1 ? iou1 : iou2;                            \
            float bbx = take1 ? pr[0] : pr[5];                               \
            float bby = take1 ? pr[1] : pr[6];                               \
            float bbw = take1 ? pr[2] : pr[7];                               \
            float bbh = take1 ? pr[3] : pr[8];                               \
            float bbc = take1 ? pr[4] : pr[9];                               \
            float dx = bbx - tb.x, dy = bby - tb.y;                          \
            float xy = dx * dx + dy * dy;                                    \
            float dw = sqrtf(bbw) - sqrtf(tb.z);                             \
            float dh = sqrtf(bbh) - sqrtf(tb.w);                             \
            float wh = dw * dw + dh * dh;                                    \
            acc_reg += xy + wh;                                              \
            float dc = bbc - best_iou;                                       \
            acc_cont += dc * dc;                                             \
        }                                                                    \
        _Pragma("unroll")                                                    \
        for (int it = 0; it < 5; ++it) {                                     \
            int q = it * 64 + lane;                                          \
            int c = q / 5;                                                   \
            int k = q - 5 * c;                                               \
            if (mi[c]) {                                                     \
                const float4 tt = ((const float4*)(bp + TC_OFF))[q];         \
                const float* pp = bp + P_OFF + c * 30 + 10 + 4 * k;          \
                float d0 = pp[0] - tt.x, d1 = pp[1] - tt.y;                  \
                float d2 = pp[2] - tt.z, d3 = pp[3] - tt.w;                  \
                acc_cls += d0 * d0 + d1 * d1 + d2 * d2 + d3 * d3;            \
            }                                                                \
        }                                                                    \
    }

    // ---- depth-2 pipeline over 4 consecutive tiles ----
    ISSUE(t0 + 0, 0)
    ISSUE(t0 + 1, 1)
    WAITV(15)            // T0 landed (T1's 15 may remain)
    COMPUTE(0)
    LGKM0
    ISSUE(t0 + 2, 0)
    WAITV(15)            // T1 landed (T2's 15 may remain)
    COMPUTE(1)
    LGKM0
    ISSUE(t0 + 3, 1)
    WAITV(15)            // T2 landed
    COMPUTE(0)
    WAITV(0)             // T3 landed (tail)
    COMPUTE(1)

#undef ISSUE
#undef WAITV
#undef LGKM0
#undef COMPUTE

    // ---- wave reduction (single wave per block) ----
    float4 vr = make_float4(acc_cls, acc_noobj, acc_reg, acc_cont);
    #pragma unroll
    for (int off = 32; off >= 1; off >>= 1) {
        vr.x += __shfl_down(vr.x, off, 64);
        vr.y += __shfl_down(vr.y, off, 64);
        vr.z += __shfl_down(vr.z, off, 64);
        vr.w += __shfl_down(vr.w, off, 64);
    }
    if (lane == 0) block_part[blockIdx.x] = vr;
}

__global__ __launch_bounds__(256) void yolo_final(
    const float4* __restrict__ part, int nparts, float* __restrict__ out, float invN)
{
    float4 v = make_float4(0.f, 0.f, 0.f, 0.f);
    for (int i = threadIdx.x; i < nparts; i += 256) {
        float4 p = part[i];
        v.x += p.x; v.y += p.y; v.z += p.z; v.w += p.w;
    }
    #pragma unroll
    for (int off = 32; off >= 1; off >>= 1) {
        v.x += __shfl_down(v.x, off, 64);
        v.y += __shfl_down(v.y, off, 64);
        v.z += __shfl_down(v.z, off, 64);
        v.w += __shfl_down(v.w, off, 64);
    }
    __shared__ float4 sred[4];
    int lane = threadIdx.x & 63;
    int wave = threadIdx.x >> 6;
    if (lane == 0) sred[wave] = v;
    __syncthreads();
    if (threadIdx.x == 0) {
        float4 r = sred[0];
        #pragma unroll
        for (int w = 1; w < 4; ++w) {
            r.x += sred[w].x; r.y += sred[w].y; r.z += sred[w].z; r.w += sred[w].w;
        }
        float cls    = r.x;
        float no_obj = 0.5f * r.y;   // L_NOOBJ
        float reg    = 5.0f * r.z;   // L_COORD
        float cont   = r.w;
        float total  = cls + no_obj + cont + reg;
        out[0] = total  * invN;
        out[1] = reg    * invN;
        out[2] = cont   * invN;
        out[3] = no_obj * invN;
        out[4] = cls    * invN;
    }
}

extern "C" void kernel_launch(void* const* d_in, const int* in_sizes, int n_in,
                              void* d_out, int out_size, void* d_ws, size_t ws_size,
                              hipStream_t stream) {
    const float* pred = (const float*)d_in[0];
    const float* tbox = (const float*)d_in[1];
    const float* tcls = (const float*)d_in[2];
    const int*   mask = (const int*)d_in[3];
    float* out = (float*)d_out;

    int cells = in_sizes[0] / 30;                 // N*S*S = 802816 (div by 256)
    int n_img = cells / (SS * SS);                // N
    int nblocks = cells / 256;                    // 4 tiles x 64 cells per block

    float4* part = (float4*)d_ws;                 // nblocks * 16 bytes

    yolo_main<<<nblocks, BLOCK, 0, stream>>>(
        (const float4*)pred, (const float4*)tbox, (const float4*)tcls,
        mask, part, cells);
    yolo_final<<<1, 256, 0, stream>>>(part, nblocks, out, 1.0f / (float)n_img);
}